// Round 1
// baseline (1118.332 us; speedup 1.0000x reference)
//
#include <hip/hip_runtime.h>

#define N_NODES 50000
#define N_EDGES 500000
#define DIM 64
#define KDIM 4
#define HID 64
#define NCLS 40

// ---- in-degree count ----
__global__ void deg_k(const int* __restrict__ dst, int* __restrict__ cnt) {
    int e = blockIdx.x * 256 + threadIdx.x;
    if (e < N_EDGES) atomicAdd(&cnt[dst[e]], 1);
}

// ---- node transform: y[n, k*64+h] = sum_d hin[n,d] * W[(k*64+d)*64 + h] ----
// block = 256 threads, 32 nodes/block. W staged in LDS (64KB), h tile padded (stride 65).
__global__ __launch_bounds__(256) void transform_k(const float* __restrict__ hin,
                                                   const float* __restrict__ W,
                                                   float* __restrict__ y) {
    __shared__ float sW[KDIM * 64 * 64];   // 16384 floats = 64 KB
    __shared__ float sh[32 * 65];          // 32 nodes x 64 dims, padded
    int t = threadIdx.x;

    // stage W: 16384 floats / 256 threads = 16 float4 each
    const float4* W4 = (const float4*)W;
    float4* sW4 = (float4*)sW;
#pragma unroll
    for (int i = 0; i < 16; ++i) sW4[t + 256 * i] = W4[t + 256 * i];

    int n0 = blockIdx.x * 32;
    // stage h tile: 2048 floats → 2 float4 per thread
#pragma unroll
    for (int i = 0; i < 2; ++i) {
        int idx = t + 256 * i;        // 0..511
        int nl = idx >> 4;            // node local 0..31
        int dg = idx & 15;            // float4 group 0..15
        int n = n0 + nl;
        float4 v = make_float4(0.f, 0.f, 0.f, 0.f);
        if (n < N_NODES) v = ((const float4*)hin)[(size_t)n * 16 + dg];
        sh[nl * 65 + dg * 4 + 0] = v.x;
        sh[nl * 65 + dg * 4 + 1] = v.y;
        sh[nl * 65 + dg * 4 + 2] = v.z;
        sh[nl * 65 + dg * 4 + 3] = v.w;
    }
    __syncthreads();

    // lane mapping: nl = t&15 (2 nodes: nl, nl+16), col group cg = t>>4
    // cols: k = cg/4, hc0 = (cg%4)*16, 16 cols per thread
    int nl = t & 15;
    int cg = t >> 4;
    int k = cg >> 2;
    int hc0 = (cg & 3) * 16;

    float acc0[16], acc1[16];
#pragma unroll
    for (int j = 0; j < 16; ++j) { acc0[j] = 0.f; acc1[j] = 0.f; }

    for (int d = 0; d < 64; ++d) {
        float a0 = sh[nl * 65 + d];
        float a1 = sh[(nl + 16) * 65 + d];
        const float* wr = &sW[k * 4096 + d * 64 + hc0];
#pragma unroll
        for (int j = 0; j < 16; ++j) {
            float w = wr[j];
            acc0[j] = fmaf(a0, w, acc0[j]);
            acc1[j] = fmaf(a1, w, acc1[j]);
        }
    }

    int n_a = n0 + nl, n_b = n0 + nl + 16;
    int cbase = k * 64 + hc0;
    if (n_a < N_NODES) {
        float4* o = (float4*)&y[(size_t)n_a * 256 + cbase];
#pragma unroll
        for (int j = 0; j < 4; ++j)
            o[j] = make_float4(acc0[4 * j], acc0[4 * j + 1], acc0[4 * j + 2], acc0[4 * j + 3]);
    }
    if (n_b < N_NODES) {
        float4* o = (float4*)&y[(size_t)n_b * 256 + cbase];
#pragma unroll
        for (int j = 0; j < 4; ++j)
            o[j] = make_float4(acc1[4 * j], acc1[4 * j + 1], acc1[4 * j + 2], acc1[4 * j + 3]);
    }
}

// ---- edge kernel: 16 lanes per edge, each lane owns 4 h-cols (float4) ----
// z[h] = b[h] + sum_k e_k * y[src, k*64+h]; s[dst,h] += relu(z[h])
__global__ __launch_bounds__(256) void edge_k(const float* __restrict__ ef,
                                              const int* __restrict__ src,
                                              const int* __restrict__ dst,
                                              const float* __restrict__ y,
                                              const float* __restrict__ b,
                                              float* __restrict__ s) {
    int t = blockIdx.x * 256 + threadIdx.x;
    int e = t >> 4;
    int lane = t & 15;
    if (e >= N_EDGES) return;

    float4 ev = ((const float4*)ef)[e];
    int sn = src[e];
    int dn = dst[e];

    const float4* yb = (const float4*)(y + (size_t)sn * 256);
    float4 v0 = yb[0 * 16 + lane];
    float4 v1 = yb[1 * 16 + lane];
    float4 v2 = yb[2 * 16 + lane];
    float4 v3 = yb[3 * 16 + lane];
    float4 acc = ((const float4*)b)[lane];

    acc.x = fmaf(ev.x, v0.x, acc.x); acc.y = fmaf(ev.x, v0.y, acc.y);
    acc.z = fmaf(ev.x, v0.z, acc.z); acc.w = fmaf(ev.x, v0.w, acc.w);
    acc.x = fmaf(ev.y, v1.x, acc.x); acc.y = fmaf(ev.y, v1.y, acc.y);
    acc.z = fmaf(ev.y, v1.z, acc.z); acc.w = fmaf(ev.y, v1.w, acc.w);
    acc.x = fmaf(ev.z, v2.x, acc.x); acc.y = fmaf(ev.z, v2.y, acc.y);
    acc.z = fmaf(ev.z, v2.z, acc.z); acc.w = fmaf(ev.z, v2.w, acc.w);
    acc.x = fmaf(ev.w, v3.x, acc.x); acc.y = fmaf(ev.w, v3.y, acc.y);
    acc.z = fmaf(ev.w, v3.z, acc.z); acc.w = fmaf(ev.w, v3.w, acc.w);

    acc.x = fmaxf(acc.x, 0.f); acc.y = fmaxf(acc.y, 0.f);
    acc.z = fmaxf(acc.z, 0.f); acc.w = fmaxf(acc.w, 0.f);

    float* sp = s + (size_t)dn * 64 + lane * 4;
    unsafeAtomicAdd(sp + 0, acc.x);
    unsafeAtomicAdd(sp + 1, acc.y);
    unsafeAtomicAdd(sp + 2, acc.z);
    unsafeAtomicAdd(sp + 3, acc.w);
}

// ---- node update: h = relu(s / max(cnt,1)) ----
__global__ void upd_k(const float* __restrict__ s, const int* __restrict__ cnt,
                      float* __restrict__ hout) {
    int t = blockIdx.x * 256 + threadIdx.x;  // over N*16 float4s
    if (t >= N_NODES * 16) return;
    int n = t >> 4;
    int c = cnt[n];
    float inv = 1.0f / (float)(c > 1 ? c : 1);
    float4 v = ((const float4*)s)[t];
    float4 r;
    r.x = fmaxf(v.x * inv, 0.f);
    r.y = fmaxf(v.y * inv, 0.f);
    r.z = fmaxf(v.z * inv, 0.f);
    r.w = fmaxf(v.w * inv, 0.f);
    ((float4*)hout)[t] = r;
}

// ---- final fc: out[n,c] = bfc[c] + sum_j h[n,j] * Wfc[j,c] ----
__global__ void fc_k(const float* __restrict__ h, const float* __restrict__ Wfc,
                     const float* __restrict__ bfc, float* __restrict__ out) {
    int t = blockIdx.x * 256 + threadIdx.x;
    if (t >= N_NODES * NCLS) return;
    int n = t / NCLS;
    int c = t - n * NCLS;
    const float* hr = h + (size_t)n * 64;
    float acc = bfc[c];
#pragma unroll
    for (int j = 0; j < 64; ++j) acc = fmaf(hr[j], Wfc[j * NCLS + c], acc);
    out[t] = acc;
}

extern "C" void kernel_launch(void* const* d_in, const int* in_sizes, int n_in,
                              void* d_out, int out_size, void* d_ws, size_t ws_size,
                              hipStream_t stream) {
    const float* nf  = (const float*)d_in[0];  // [N, 64]
    const float* ef  = (const float*)d_in[1];  // [2, E, 4]
    const int*   src = (const int*)d_in[2];    // [E]
    const int*   dst = (const int*)d_in[3];    // [E]
    const float* W0  = (const float*)d_in[4];  // [256, 64]
    const float* b0  = (const float*)d_in[5];  // [64]
    const float* W1  = (const float*)d_in[6];  // [256, 64]
    const float* b1  = (const float*)d_in[7];  // [64]
    const float* Wfc = (const float*)d_in[8];  // [64, 40]
    const float* bfc = (const float*)d_in[9];  // [40]
    float* out = (float*)d_out;

    char* ws = (char*)d_ws;
    size_t off = 0;
    auto alloc = [&](size_t bytes) -> void* {
        void* p = ws + off;
        off = (off + bytes + 255) & ~(size_t)255;
        return p;
    };
    int*   cnt  = (int*)  alloc((size_t)N_NODES * 4);
    float* y    = (float*)alloc((size_t)N_NODES * 256 * 4);
    float* sbuf = (float*)alloc((size_t)N_NODES * 64 * 4);
    float* h1   = (float*)alloc((size_t)N_NODES * 64 * 4);
    float* h2   = (float*)alloc((size_t)N_NODES * 64 * 4);

    hipMemsetAsync(cnt, 0, (size_t)N_NODES * 4, stream);
    hipMemsetAsync(sbuf, 0, (size_t)N_NODES * 64 * 4, stream);
    deg_k<<<(N_EDGES + 255) / 256, 256, 0, stream>>>(dst, cnt);

    int tgrid = (N_NODES + 31) / 32;
    int egrid = (N_EDGES * 16 + 255) / 256;
    int ugrid = (N_NODES * 16 + 255) / 256;

    // layer 0
    transform_k<<<tgrid, 256, 0, stream>>>(nf, W0, y);
    edge_k<<<egrid, 256, 0, stream>>>(ef, src, dst, y, b0, sbuf);
    upd_k<<<ugrid, 256, 0, stream>>>(sbuf, cnt, h1);

    // layer 1
    hipMemsetAsync(sbuf, 0, (size_t)N_NODES * 64 * 4, stream);
    transform_k<<<tgrid, 256, 0, stream>>>(h1, W1, y);
    edge_k<<<egrid, 256, 0, stream>>>(ef + (size_t)N_EDGES * 4, src, dst, y, b1, sbuf);
    upd_k<<<ugrid, 256, 0, stream>>>(sbuf, cnt, h2);

    // classifier
    fc_k<<<(N_NODES * NCLS + 255) / 256, 256, 0, stream>>>(h2, Wfc, bfc, out);
}

// Round 2
// 549.710 us; speedup vs baseline: 2.0344x; 2.0344x over previous
//
#include <hip/hip_runtime.h>

#define N_NODES 50000
#define N_EDGES 500000
#define DIM 64
#define KDIM 4
#define HID 64
#define NCLS 40

// ---- histogram of dst (also the in-degree) ----
__global__ void hist_k(const int* __restrict__ dst, int* __restrict__ cnt) {
    int e = blockIdx.x * 256 + threadIdx.x;
    if (e < N_EDGES) atomicAdd(&cnt[dst[e]], 1);
}

// ---- single-workgroup exclusive scan of cnt[50000] -> start[], cursor[] ----
__global__ __launch_bounds__(1024) void scan_k(const int* __restrict__ cnt,
                                               int* __restrict__ start,
                                               int* __restrict__ cursor) {
    __shared__ int lsum[1024];
    const int CH = (N_NODES + 1023) / 1024;  // 49
    int t = threadIdx.x;
    int base = t * CH;
    int s = 0;
    for (int j = 0; j < CH; ++j) {
        int idx = base + j;
        if (idx < N_NODES) s += cnt[idx];
    }
    lsum[t] = s;
    __syncthreads();
    // Hillis-Steele inclusive scan over 1024 entries
    for (int off = 1; off < 1024; off <<= 1) {
        int v = (t >= off) ? lsum[t - off] : 0;
        __syncthreads();
        lsum[t] += v;
        __syncthreads();
    }
    int run = (t == 0) ? 0 : lsum[t - 1];  // exclusive prefix of this chunk
    for (int j = 0; j < CH; ++j) {
        int idx = base + j;
        if (idx < N_NODES) {
            start[idx] = run;
            cursor[idx] = run;
            run += cnt[idx];
        }
    }
    if (t == 0) start[N_NODES] = N_EDGES;
}

// ---- counting-sort scatter: perm grouped by dst ----
__global__ void scatter_k(const int* __restrict__ dst, int* __restrict__ cursor,
                          int* __restrict__ perm) {
    int e = blockIdx.x * 256 + threadIdx.x;
    if (e < N_EDGES) {
        int d = dst[e];
        int pos = atomicAdd(&cursor[d], 1);
        perm[pos] = e;
    }
}

// ---- node transform: y[n, k*64+h] = sum_d hin[n,d] * W[(k*64+d)*64 + h] ----
// block = 256 threads, 32 nodes/block. W staged in LDS (64KB), h tile padded.
__global__ __launch_bounds__(256) void transform_k(const float* __restrict__ hin,
                                                   const float* __restrict__ W,
                                                   float* __restrict__ y) {
    __shared__ float sW[KDIM * 64 * 64];   // 16384 floats = 64 KB
    __shared__ float sh[32 * 65];          // 32 nodes x 64 dims, padded
    int t = threadIdx.x;

    const float4* W4 = (const float4*)W;
    float4* sW4 = (float4*)sW;
#pragma unroll
    for (int i = 0; i < 16; ++i) sW4[t + 256 * i] = W4[t + 256 * i];

    int n0 = blockIdx.x * 32;
#pragma unroll
    for (int i = 0; i < 2; ++i) {
        int idx = t + 256 * i;        // 0..511
        int nl = idx >> 4;            // node local 0..31
        int dg = idx & 15;            // float4 group 0..15
        int n = n0 + nl;
        float4 v = make_float4(0.f, 0.f, 0.f, 0.f);
        if (n < N_NODES) v = ((const float4*)hin)[(size_t)n * 16 + dg];
        sh[nl * 65 + dg * 4 + 0] = v.x;
        sh[nl * 65 + dg * 4 + 1] = v.y;
        sh[nl * 65 + dg * 4 + 2] = v.z;
        sh[nl * 65 + dg * 4 + 3] = v.w;
    }
    __syncthreads();

    int nl = t & 15;
    int cg = t >> 4;
    int k = cg >> 2;
    int hc0 = (cg & 3) * 16;

    float acc0[16], acc1[16];
#pragma unroll
    for (int j = 0; j < 16; ++j) { acc0[j] = 0.f; acc1[j] = 0.f; }

    for (int d = 0; d < 64; ++d) {
        float a0 = sh[nl * 65 + d];
        float a1 = sh[(nl + 16) * 65 + d];
        const float* wr = &sW[k * 4096 + d * 64 + hc0];
#pragma unroll
        for (int j = 0; j < 16; ++j) {
            float w = wr[j];
            acc0[j] = fmaf(a0, w, acc0[j]);
            acc1[j] = fmaf(a1, w, acc1[j]);
        }
    }

    int n_a = n0 + nl, n_b = n0 + nl + 16;
    int cbase = k * 64 + hc0;
    if (n_a < N_NODES) {
        float4* o = (float4*)&y[(size_t)n_a * 256 + cbase];
#pragma unroll
        for (int j = 0; j < 4; ++j)
            o[j] = make_float4(acc0[4 * j], acc0[4 * j + 1], acc0[4 * j + 2], acc0[4 * j + 3]);
    }
    if (n_b < N_NODES) {
        float4* o = (float4*)&y[(size_t)n_b * 256 + cbase];
#pragma unroll
        for (int j = 0; j < 4; ++j)
            o[j] = make_float4(acc1[4 * j], acc1[4 * j + 1], acc1[4 * j + 2], acc1[4 * j + 3]);
    }
}

// ---- per-node gather-aggregate: 16 lanes per node, no atomics ----
// for each in-edge: z = b + sum_k ef[e,k]*y[src,k*64+:]; acc += relu(z)
// then h[n] = relu(acc / max(deg,1))
__global__ __launch_bounds__(256) void agg_k(const float* __restrict__ ef,
                                             const int* __restrict__ src,
                                             const int* __restrict__ perm,
                                             const int* __restrict__ start,
                                             const int* __restrict__ cnt,
                                             const float* __restrict__ y,
                                             const float* __restrict__ b,
                                             float* __restrict__ hout) {
    int t = blockIdx.x * 256 + threadIdx.x;
    int g = t >> 4;       // node
    int lane = t & 15;    // float4 column group
    if (g >= N_NODES) return;

    int s0 = start[g];
    int deg = cnt[g];
    int s1 = s0 + deg;

    float4 bias = ((const float4*)b)[lane];
    float4 acc = make_float4(0.f, 0.f, 0.f, 0.f);

    for (int i = s0; i < s1; ++i) {
        int e = perm[i];
        float4 ev = ((const float4*)ef)[e];
        int sn = src[e];
        const float4* yb = (const float4*)(y + (size_t)sn * 256);
        float4 v0 = yb[0 * 16 + lane];
        float4 v1 = yb[1 * 16 + lane];
        float4 v2 = yb[2 * 16 + lane];
        float4 v3 = yb[3 * 16 + lane];

        float4 z = bias;
        z.x = fmaf(ev.x, v0.x, z.x); z.y = fmaf(ev.x, v0.y, z.y);
        z.z = fmaf(ev.x, v0.z, z.z); z.w = fmaf(ev.x, v0.w, z.w);
        z.x = fmaf(ev.y, v1.x, z.x); z.y = fmaf(ev.y, v1.y, z.y);
        z.z = fmaf(ev.y, v1.z, z.z); z.w = fmaf(ev.y, v1.w, z.w);
        z.x = fmaf(ev.z, v2.x, z.x); z.y = fmaf(ev.z, v2.y, z.y);
        z.z = fmaf(ev.z, v2.z, z.z); z.w = fmaf(ev.z, v2.w, z.w);
        z.x = fmaf(ev.w, v3.x, z.x); z.y = fmaf(ev.w, v3.y, z.y);
        z.z = fmaf(ev.w, v3.z, z.z); z.w = fmaf(ev.w, v3.w, z.w);

        acc.x += fmaxf(z.x, 0.f);
        acc.y += fmaxf(z.y, 0.f);
        acc.z += fmaxf(z.z, 0.f);
        acc.w += fmaxf(z.w, 0.f);
    }

    float inv = 1.0f / (float)(deg > 1 ? deg : 1);
    float4 r;
    r.x = fmaxf(acc.x * inv, 0.f);
    r.y = fmaxf(acc.y * inv, 0.f);
    r.z = fmaxf(acc.z * inv, 0.f);
    r.w = fmaxf(acc.w * inv, 0.f);
    ((float4*)hout)[(size_t)g * 16 + lane] = r;
}

// ---- final fc: out[n,c] = bfc[c] + sum_j h[n,j] * Wfc[j,c] ----
__global__ void fc_k(const float* __restrict__ h, const float* __restrict__ Wfc,
                     const float* __restrict__ bfc, float* __restrict__ out) {
    int t = blockIdx.x * 256 + threadIdx.x;
    if (t >= N_NODES * NCLS) return;
    int n = t / NCLS;
    int c = t - n * NCLS;
    const float* hr = h + (size_t)n * 64;
    float acc = bfc[c];
#pragma unroll
    for (int j = 0; j < 64; ++j) acc = fmaf(hr[j], Wfc[j * NCLS + c], acc);
    out[t] = acc;
}

extern "C" void kernel_launch(void* const* d_in, const int* in_sizes, int n_in,
                              void* d_out, int out_size, void* d_ws, size_t ws_size,
                              hipStream_t stream) {
    const float* nf  = (const float*)d_in[0];  // [N, 64]
    const float* ef  = (const float*)d_in[1];  // [2, E, 4]
    const int*   src = (const int*)d_in[2];    // [E]
    const int*   dst = (const int*)d_in[3];    // [E]
    const float* W0  = (const float*)d_in[4];  // [256, 64]
    const float* b0  = (const float*)d_in[5];  // [64]
    const float* W1  = (const float*)d_in[6];  // [256, 64]
    const float* b1  = (const float*)d_in[7];  // [64]
    const float* Wfc = (const float*)d_in[8];  // [64, 40]
    const float* bfc = (const float*)d_in[9];  // [40]
    float* out = (float*)d_out;

    char* ws = (char*)d_ws;
    size_t off = 0;
    auto alloc = [&](size_t bytes) -> void* {
        void* p = ws + off;
        off = (off + bytes + 255) & ~(size_t)255;
        return p;
    };
    int*   cnt    = (int*)  alloc((size_t)N_NODES * 4);
    int*   start  = (int*)  alloc((size_t)(N_NODES + 1) * 4);
    int*   cursor = (int*)  alloc((size_t)N_NODES * 4);
    int*   perm   = (int*)  alloc((size_t)N_EDGES * 4);
    float* y      = (float*)alloc((size_t)N_NODES * 256 * 4);
    float* h1     = (float*)alloc((size_t)N_NODES * 64 * 4);
    float* h2     = (float*)alloc((size_t)N_NODES * 64 * 4);

    hipMemsetAsync(cnt, 0, (size_t)N_NODES * 4, stream);

    // build CSR by dst (counting sort)
    hist_k<<<(N_EDGES + 255) / 256, 256, 0, stream>>>(dst, cnt);
    scan_k<<<1, 1024, 0, stream>>>(cnt, start, cursor);
    scatter_k<<<(N_EDGES + 255) / 256, 256, 0, stream>>>(dst, cursor, perm);

    int tgrid = (N_NODES + 31) / 32;
    int agrid = (N_NODES * 16 + 255) / 256;

    // layer 0
    transform_k<<<tgrid, 256, 0, stream>>>(nf, W0, y);
    agg_k<<<agrid, 256, 0, stream>>>(ef, src, perm, start, cnt, y, b0, h1);

    // layer 1
    transform_k<<<tgrid, 256, 0, stream>>>(h1, W1, y);
    agg_k<<<agrid, 256, 0, stream>>>(ef + (size_t)N_EDGES * 4, src, perm, start, cnt, y, b1, h2);

    // classifier
    fc_k<<<(N_NODES * NCLS + 255) / 256, 256, 0, stream>>>(h2, Wfc, bfc, out);
}

// Round 3
// 412.021 us; speedup vs baseline: 2.7143x; 1.3342x over previous
//
#include <hip/hip_runtime.h>

#define N_NODES 50000
#define N_EDGES 500000
#define DIM 64
#define KDIM 4
#define HID 64
#define NCLS 40
#define NBLK ((N_NODES + 255) / 256)   // 196

// ---- histogram of dst (in-degree) ----
__global__ void hist_k(const int* __restrict__ dst, int* __restrict__ cnt) {
    int e = blockIdx.x * 256 + threadIdx.x;
    if (e < N_EDGES) atomicAdd(&cnt[dst[e]], 1);
}

// ---- hierarchical scan, stage 1: per-block exclusive scan + block sums ----
__global__ __launch_bounds__(256) void blk_scan_k(const int* __restrict__ cnt,
                                                  int* __restrict__ esc,
                                                  int* __restrict__ bsum) {
    __shared__ int ls[256];
    int t = threadIdx.x;
    int n = blockIdx.x * 256 + t;
    int v = (n < N_NODES) ? cnt[n] : 0;
    ls[t] = v;
    __syncthreads();
#pragma unroll
    for (int off = 1; off < 256; off <<= 1) {
        int u = (t >= off) ? ls[t - off] : 0;
        __syncthreads();
        ls[t] += u;
        __syncthreads();
    }
    if (n < N_NODES) esc[n] = ls[t] - v;   // exclusive within block
    if (t == 255) bsum[blockIdx.x] = ls[255];
}

// ---- stage 2: scan the 196 block sums (single block) ----
__global__ __launch_bounds__(256) void bsum_scan_k(const int* __restrict__ bsum,
                                                   int* __restrict__ boff,
                                                   int* __restrict__ start) {
    __shared__ int ls[256];
    int t = threadIdx.x;
    int v = (t < NBLK) ? bsum[t] : 0;
    ls[t] = v;
    __syncthreads();
#pragma unroll
    for (int off = 1; off < 256; off <<= 1) {
        int u = (t >= off) ? ls[t - off] : 0;
        __syncthreads();
        ls[t] += u;
        __syncthreads();
    }
    if (t < NBLK) boff[t] = ls[t] - v;     // exclusive block offset
    if (t == 0) start[N_NODES] = N_EDGES;
}

// ---- stage 3: finalize start/cursor ----
__global__ void finalize_k(const int* __restrict__ esc, const int* __restrict__ boff,
                           int* __restrict__ start, int* __restrict__ cursor) {
    int n = blockIdx.x * 256 + threadIdx.x;
    if (n < N_NODES) {
        int s = esc[n] + boff[blockIdx.x];
        start[n] = s;
        cursor[n] = s;
    }
}

// ---- counting-sort scatter of the edge PAYLOAD (no perm indirection) ----
__global__ void scatter_k(const int* __restrict__ src, const int* __restrict__ dst,
                          const float* __restrict__ ef, int* __restrict__ cursor,
                          int* __restrict__ srcp, float4* __restrict__ efp0,
                          float4* __restrict__ efp1) {
    int e = blockIdx.x * 256 + threadIdx.x;
    if (e < N_EDGES) {
        int d = dst[e];
        int pos = atomicAdd(&cursor[d], 1);
        srcp[pos] = src[e];
        efp0[pos] = ((const float4*)ef)[e];
        efp1[pos] = ((const float4*)ef)[N_EDGES + e];
    }
}

// ---- node transform: y[n, k*64+h] = sum_d hin[n,d] * W[(k*64+d)*64 + h] ----
__global__ __launch_bounds__(256) void transform_k(const float* __restrict__ hin,
                                                   const float* __restrict__ W,
                                                   float* __restrict__ y) {
    __shared__ float sW[KDIM * 64 * 64];   // 64 KB
    __shared__ float sh[32 * 65];
    int t = threadIdx.x;

    const float4* W4 = (const float4*)W;
    float4* sW4 = (float4*)sW;
#pragma unroll
    for (int i = 0; i < 16; ++i) sW4[t + 256 * i] = W4[t + 256 * i];

    int n0 = blockIdx.x * 32;
#pragma unroll
    for (int i = 0; i < 2; ++i) {
        int idx = t + 256 * i;
        int nl = idx >> 4;
        int dg = idx & 15;
        int n = n0 + nl;
        float4 v = make_float4(0.f, 0.f, 0.f, 0.f);
        if (n < N_NODES) v = ((const float4*)hin)[(size_t)n * 16 + dg];
        sh[nl * 65 + dg * 4 + 0] = v.x;
        sh[nl * 65 + dg * 4 + 1] = v.y;
        sh[nl * 65 + dg * 4 + 2] = v.z;
        sh[nl * 65 + dg * 4 + 3] = v.w;
    }
    __syncthreads();

    int nl = t & 15;
    int cg = t >> 4;
    int k = cg >> 2;
    int hc0 = (cg & 3) * 16;

    float acc0[16], acc1[16];
#pragma unroll
    for (int j = 0; j < 16; ++j) { acc0[j] = 0.f; acc1[j] = 0.f; }

    for (int d = 0; d < 64; ++d) {
        float a0 = sh[nl * 65 + d];
        float a1 = sh[(nl + 16) * 65 + d];
        const float* wr = &sW[k * 4096 + d * 64 + hc0];
#pragma unroll
        for (int j = 0; j < 16; ++j) {
            float w = wr[j];
            acc0[j] = fmaf(a0, w, acc0[j]);
            acc1[j] = fmaf(a1, w, acc1[j]);
        }
    }

    int n_a = n0 + nl, n_b = n0 + nl + 16;
    int cbase = k * 64 + hc0;
    if (n_a < N_NODES) {
        float4* o = (float4*)&y[(size_t)n_a * 256 + cbase];
#pragma unroll
        for (int j = 0; j < 4; ++j)
            o[j] = make_float4(acc0[4 * j], acc0[4 * j + 1], acc0[4 * j + 2], acc0[4 * j + 3]);
    }
    if (n_b < N_NODES) {
        float4* o = (float4*)&y[(size_t)n_b * 256 + cbase];
#pragma unroll
        for (int j = 0; j < 4; ++j)
            o[j] = make_float4(acc1[4 * j], acc1[4 * j + 1], acc1[4 * j + 2], acc1[4 * j + 3]);
    }
}

// ---- per-node gather-aggregate: 16 lanes per node, no atomics, 2x unroll ----
__global__ __launch_bounds__(256) void agg_k(const int* __restrict__ srcp,
                                             const float4* __restrict__ efp,
                                             const int* __restrict__ start,
                                             const int* __restrict__ cnt,
                                             const float* __restrict__ y,
                                             const float* __restrict__ b,
                                             float* __restrict__ hout) {
    int t = blockIdx.x * 256 + threadIdx.x;
    int g = t >> 4;
    int lane = t & 15;
    if (g >= N_NODES) return;

    int s0 = start[g];
    int deg = cnt[g];
    int s1 = s0 + deg;

    float4 bias = ((const float4*)b)[lane];
    float4 acc = make_float4(0.f, 0.f, 0.f, 0.f);

    int i = s0;
    for (; i + 2 <= s1; i += 2) {
        int sn0 = srcp[i];
        int sn1 = srcp[i + 1];
        float4 e0 = efp[i];
        float4 e1 = efp[i + 1];
        const float4* ya = (const float4*)(y + (size_t)sn0 * 256);
        const float4* yb = (const float4*)(y + (size_t)sn1 * 256);
        float4 a0 = ya[lane], a1 = ya[16 + lane], a2 = ya[32 + lane], a3 = ya[48 + lane];
        float4 c0 = yb[lane], c1 = yb[16 + lane], c2 = yb[32 + lane], c3 = yb[48 + lane];

        float4 z = bias;
        z.x = fmaf(e0.x, a0.x, z.x); z.y = fmaf(e0.x, a0.y, z.y);
        z.z = fmaf(e0.x, a0.z, z.z); z.w = fmaf(e0.x, a0.w, z.w);
        z.x = fmaf(e0.y, a1.x, z.x); z.y = fmaf(e0.y, a1.y, z.y);
        z.z = fmaf(e0.y, a1.z, z.z); z.w = fmaf(e0.y, a1.w, z.w);
        z.x = fmaf(e0.z, a2.x, z.x); z.y = fmaf(e0.z, a2.y, z.y);
        z.z = fmaf(e0.z, a2.z, z.z); z.w = fmaf(e0.z, a2.w, z.w);
        z.x = fmaf(e0.w, a3.x, z.x); z.y = fmaf(e0.w, a3.y, z.y);
        z.z = fmaf(e0.w, a3.z, z.z); z.w = fmaf(e0.w, a3.w, z.w);
        acc.x += fmaxf(z.x, 0.f); acc.y += fmaxf(z.y, 0.f);
        acc.z += fmaxf(z.z, 0.f); acc.w += fmaxf(z.w, 0.f);

        float4 w = bias;
        w.x = fmaf(e1.x, c0.x, w.x); w.y = fmaf(e1.x, c0.y, w.y);
        w.z = fmaf(e1.x, c0.z, w.z); w.w = fmaf(e1.x, c0.w, w.w);
        w.x = fmaf(e1.y, c1.x, w.x); w.y = fmaf(e1.y, c1.y, w.y);
        w.z = fmaf(e1.y, c1.z, w.z); w.w = fmaf(e1.y, c1.w, w.w);
        w.x = fmaf(e1.z, c2.x, w.x); w.y = fmaf(e1.z, c2.y, w.y);
        w.z = fmaf(e1.z, c2.z, w.z); w.w = fmaf(e1.z, c2.w, w.w);
        w.x = fmaf(e1.w, c3.x, w.x); w.y = fmaf(e1.w, c3.y, w.y);
        w.z = fmaf(e1.w, c3.z, w.z); w.w = fmaf(e1.w, c3.w, w.w);
        acc.x += fmaxf(w.x, 0.f); acc.y += fmaxf(w.y, 0.f);
        acc.z += fmaxf(w.z, 0.f); acc.w += fmaxf(w.w, 0.f);
    }
    if (i < s1) {
        int sn0 = srcp[i];
        float4 e0 = efp[i];
        const float4* ya = (const float4*)(y + (size_t)sn0 * 256);
        float4 a0 = ya[lane], a1 = ya[16 + lane], a2 = ya[32 + lane], a3 = ya[48 + lane];
        float4 z = bias;
        z.x = fmaf(e0.x, a0.x, z.x); z.y = fmaf(e0.x, a0.y, z.y);
        z.z = fmaf(e0.x, a0.z, z.z); z.w = fmaf(e0.x, a0.w, z.w);
        z.x = fmaf(e0.y, a1.x, z.x); z.y = fmaf(e0.y, a1.y, z.y);
        z.z = fmaf(e0.y, a1.z, z.z); z.w = fmaf(e0.y, a1.w, z.w);
        z.x = fmaf(e0.z, a2.x, z.x); z.y = fmaf(e0.z, a2.y, z.y);
        z.z = fmaf(e0.z, a2.z, z.z); z.w = fmaf(e0.z, a2.w, z.w);
        z.x = fmaf(e0.w, a3.x, z.x); z.y = fmaf(e0.w, a3.y, z.y);
        z.z = fmaf(e0.w, a3.z, z.z); z.w = fmaf(e0.w, a3.w, z.w);
        acc.x += fmaxf(z.x, 0.f); acc.y += fmaxf(z.y, 0.f);
        acc.z += fmaxf(z.z, 0.f); acc.w += fmaxf(z.w, 0.f);
    }

    float inv = 1.0f / (float)(deg > 1 ? deg : 1);
    float4 r;
    r.x = fmaxf(acc.x * inv, 0.f);
    r.y = fmaxf(acc.y * inv, 0.f);
    r.z = fmaxf(acc.z * inv, 0.f);
    r.w = fmaxf(acc.w * inv, 0.f);
    ((float4*)hout)[(size_t)g * 16 + lane] = r;
}

// ---- final fc ----
__global__ void fc_k(const float* __restrict__ h, const float* __restrict__ Wfc,
                     const float* __restrict__ bfc, float* __restrict__ out) {
    int t = blockIdx.x * 256 + threadIdx.x;
    if (t >= N_NODES * NCLS) return;
    int n = t / NCLS;
    int c = t - n * NCLS;
    const float* hr = h + (size_t)n * 64;
    float acc = bfc[c];
#pragma unroll
    for (int j = 0; j < 64; ++j) acc = fmaf(hr[j], Wfc[j * NCLS + c], acc);
    out[t] = acc;
}

extern "C" void kernel_launch(void* const* d_in, const int* in_sizes, int n_in,
                              void* d_out, int out_size, void* d_ws, size_t ws_size,
                              hipStream_t stream) {
    const float* nf  = (const float*)d_in[0];
    const float* ef  = (const float*)d_in[1];
    const int*   src = (const int*)d_in[2];
    const int*   dst = (const int*)d_in[3];
    const float* W0  = (const float*)d_in[4];
    const float* b0  = (const float*)d_in[5];
    const float* W1  = (const float*)d_in[6];
    const float* b1  = (const float*)d_in[7];
    const float* Wfc = (const float*)d_in[8];
    const float* bfc = (const float*)d_in[9];
    float* out = (float*)d_out;

    char* ws = (char*)d_ws;
    size_t off = 0;
    auto alloc = [&](size_t bytes) -> void* {
        void* p = ws + off;
        off = (off + bytes + 255) & ~(size_t)255;
        return p;
    };
    int*    cnt    = (int*)   alloc((size_t)N_NODES * 4);
    int*    esc    = (int*)   alloc((size_t)N_NODES * 4);
    int*    bsum   = (int*)   alloc((size_t)NBLK * 4);
    int*    boff   = (int*)   alloc((size_t)NBLK * 4);
    int*    start  = (int*)   alloc((size_t)(N_NODES + 1) * 4);
    int*    cursor = (int*)   alloc((size_t)N_NODES * 4);
    int*    srcp   = (int*)   alloc((size_t)N_EDGES * 4);
    float4* efp0   = (float4*)alloc((size_t)N_EDGES * 16);
    float4* efp1   = (float4*)alloc((size_t)N_EDGES * 16);
    float*  y      = (float*) alloc((size_t)N_NODES * 256 * 4);
    float*  hbuf   = (float*) alloc((size_t)N_NODES * 64 * 4);

    hipMemsetAsync(cnt, 0, (size_t)N_NODES * 4, stream);

    // CSR build
    hist_k<<<(N_EDGES + 255) / 256, 256, 0, stream>>>(dst, cnt);
    blk_scan_k<<<NBLK, 256, 0, stream>>>(cnt, esc, bsum);
    bsum_scan_k<<<1, 256, 0, stream>>>(bsum, boff, start);
    finalize_k<<<NBLK, 256, 0, stream>>>(esc, boff, start, cursor);
    scatter_k<<<(N_EDGES + 255) / 256, 256, 0, stream>>>(src, dst, ef, cursor, srcp, efp0, efp1);

    int tgrid = (N_NODES + 31) / 32;
    int agrid = (N_NODES * 16 + 255) / 256;

    // layer 0
    transform_k<<<tgrid, 256, 0, stream>>>(nf, W0, y);
    agg_k<<<agrid, 256, 0, stream>>>(srcp, efp0, start, cnt, y, b0, hbuf);

    // layer 1
    transform_k<<<tgrid, 256, 0, stream>>>(hbuf, W1, y);
    agg_k<<<agrid, 256, 0, stream>>>(srcp, efp1, start, cnt, y, b1, hbuf);

    // classifier
    fc_k<<<(N_NODES * NCLS + 255) / 256, 256, 0, stream>>>(hbuf, Wfc, bfc, out);
}

// Round 4
// 322.262 us; speedup vs baseline: 3.4703x; 1.2785x over previous
//
#include <hip/hip_runtime.h>
#include <hip/hip_fp16.h>

#define N_NODES 50000
#define N_EDGES 500000
#define DIM 64
#define KDIM 4
#define HID 64
#define NCLS 40
#define NBLK ((N_NODES + 255) / 256)   // 196

__device__ inline unsigned pack2(float a, float b) {
    __half2 h = __floats2half2_rn(a, b);
    return *(unsigned*)&h;
}
__device__ inline float2 unpack2(unsigned u) {
    __half2 h = *(__half2*)&u;
    return __half22float2(h);
}

// ---- histogram of dst (in-degree) ----
__global__ void hist_k(const int* __restrict__ dst, int* __restrict__ cnt) {
    int e = blockIdx.x * 256 + threadIdx.x;
    if (e < N_EDGES) atomicAdd(&cnt[dst[e]], 1);
}

// ---- hierarchical scan, stage 1 ----
__global__ __launch_bounds__(256) void blk_scan_k(const int* __restrict__ cnt,
                                                  int* __restrict__ esc,
                                                  int* __restrict__ bsum) {
    __shared__ int ls[256];
    int t = threadIdx.x;
    int n = blockIdx.x * 256 + t;
    int v = (n < N_NODES) ? cnt[n] : 0;
    ls[t] = v;
    __syncthreads();
#pragma unroll
    for (int off = 1; off < 256; off <<= 1) {
        int u = (t >= off) ? ls[t - off] : 0;
        __syncthreads();
        ls[t] += u;
        __syncthreads();
    }
    if (n < N_NODES) esc[n] = ls[t] - v;
    if (t == 255) bsum[blockIdx.x] = ls[255];
}

// ---- stage 2: scan 196 block sums ----
__global__ __launch_bounds__(256) void bsum_scan_k(const int* __restrict__ bsum,
                                                   int* __restrict__ boff,
                                                   int* __restrict__ start) {
    __shared__ int ls[256];
    int t = threadIdx.x;
    int v = (t < NBLK) ? bsum[t] : 0;
    ls[t] = v;
    __syncthreads();
#pragma unroll
    for (int off = 1; off < 256; off <<= 1) {
        int u = (t >= off) ? ls[t - off] : 0;
        __syncthreads();
        ls[t] += u;
        __syncthreads();
    }
    if (t < NBLK) boff[t] = ls[t] - v;
    if (t == 0) start[N_NODES] = N_EDGES;
}

// ---- stage 3: finalize ----
__global__ void finalize_k(const int* __restrict__ esc, const int* __restrict__ boff,
                           int* __restrict__ start, int* __restrict__ cursor) {
    int n = blockIdx.x * 256 + threadIdx.x;
    if (n < N_NODES) {
        int s = esc[n] + boff[blockIdx.x];
        start[n] = s;
        cursor[n] = s;
    }
}

// ---- counting-sort scatter of 16B edge records {src, e(half4), 0} per layer ----
__global__ void scatter_k(const int* __restrict__ src, const int* __restrict__ dst,
                          const float* __restrict__ ef, int* __restrict__ cursor,
                          uint4* __restrict__ rec0, uint4* __restrict__ rec1) {
    int e = blockIdx.x * 256 + threadIdx.x;
    if (e < N_EDGES) {
        int d = dst[e];
        int pos = atomicAdd(&cursor[d], 1);
        int sn = src[e];
        float4 f0 = ((const float4*)ef)[e];
        float4 f1 = ((const float4*)ef)[N_EDGES + e];
        uint4 r0 = make_uint4((unsigned)sn, pack2(f0.x, f0.y), pack2(f0.z, f0.w), 0u);
        uint4 r1 = make_uint4((unsigned)sn, pack2(f1.x, f1.y), pack2(f1.z, f1.w), 0u);
        rec0[pos] = r0;
        rec1[pos] = r1;
    }
}

// ---- node transform: y[n, k*64+h] = sum_d hin[n,d] * W[(k*64+d)*64+h], fp16 out ----
__global__ __launch_bounds__(256) void transform_k(const float* __restrict__ hin,
                                                   const float* __restrict__ W,
                                                   unsigned* __restrict__ y) {
    __shared__ float sW[KDIM * 64 * 64];   // 64 KB
    __shared__ float sh[32 * 65];
    int t = threadIdx.x;

    const float4* W4 = (const float4*)W;
    float4* sW4 = (float4*)sW;
#pragma unroll
    for (int i = 0; i < 16; ++i) sW4[t + 256 * i] = W4[t + 256 * i];

    int n0 = blockIdx.x * 32;
#pragma unroll
    for (int i = 0; i < 2; ++i) {
        int idx = t + 256 * i;
        int nl = idx >> 4;
        int dg = idx & 15;
        int n = n0 + nl;
        float4 v = make_float4(0.f, 0.f, 0.f, 0.f);
        if (n < N_NODES) v = ((const float4*)hin)[(size_t)n * 16 + dg];
        sh[nl * 65 + dg * 4 + 0] = v.x;
        sh[nl * 65 + dg * 4 + 1] = v.y;
        sh[nl * 65 + dg * 4 + 2] = v.z;
        sh[nl * 65 + dg * 4 + 3] = v.w;
    }
    __syncthreads();

    int nl = t & 15;
    int cg = t >> 4;
    int k = cg >> 2;
    int hc0 = (cg & 3) * 16;

    float acc0[16], acc1[16];
#pragma unroll
    for (int j = 0; j < 16; ++j) { acc0[j] = 0.f; acc1[j] = 0.f; }

    for (int d = 0; d < 64; ++d) {
        float a0 = sh[nl * 65 + d];
        float a1 = sh[(nl + 16) * 65 + d];
        const float* wr = &sW[k * 4096 + d * 64 + hc0];
#pragma unroll
        for (int j = 0; j < 16; ++j) {
            float w = wr[j];
            acc0[j] = fmaf(a0, w, acc0[j]);
            acc1[j] = fmaf(a1, w, acc1[j]);
        }
    }

    int n_a = n0 + nl, n_b = n0 + nl + 16;
    int cbase = k * 64 + hc0;
    if (n_a < N_NODES) {
        uint4* o = (uint4*)(y + ((size_t)n_a * 256 + cbase) / 2);
        o[0] = make_uint4(pack2(acc0[0], acc0[1]), pack2(acc0[2], acc0[3]),
                          pack2(acc0[4], acc0[5]), pack2(acc0[6], acc0[7]));
        o[1] = make_uint4(pack2(acc0[8], acc0[9]), pack2(acc0[10], acc0[11]),
                          pack2(acc0[12], acc0[13]), pack2(acc0[14], acc0[15]));
    }
    if (n_b < N_NODES) {
        uint4* o = (uint4*)(y + ((size_t)n_b * 256 + cbase) / 2);
        o[0] = make_uint4(pack2(acc1[0], acc1[1]), pack2(acc1[2], acc1[3]),
                          pack2(acc1[4], acc1[5]), pack2(acc1[6], acc1[7]));
        o[1] = make_uint4(pack2(acc1[8], acc1[9]), pack2(acc1[10], acc1[11]),
                          pack2(acc1[12], acc1[13]), pack2(acc1[14], acc1[15]));
    }
}

// ---- per-edge inner step (fp16 y) ----
__device__ inline void edge_step(const uint4 r, const unsigned* __restrict__ y,
                                 int lane, const float4 bias, float4& acc) {
    int sn = (int)r.x;
    float2 e01 = unpack2(r.y);
    float2 e23 = unpack2(r.z);
    const uint2* yb = (const uint2*)(y + (size_t)sn * 128);  // 256 halfs
    uint2 q0 = yb[lane];
    uint2 q1 = yb[16 + lane];
    uint2 q2 = yb[32 + lane];
    uint2 q3 = yb[48 + lane];

    float2 a0 = unpack2(q0.x), a1 = unpack2(q0.y);
    float2 b0 = unpack2(q1.x), b1 = unpack2(q1.y);
    float2 c0 = unpack2(q2.x), c1 = unpack2(q2.y);
    float2 d0 = unpack2(q3.x), d1 = unpack2(q3.y);

    float4 z = bias;
    z.x = fmaf(e01.x, a0.x, z.x); z.y = fmaf(e01.x, a0.y, z.y);
    z.z = fmaf(e01.x, a1.x, z.z); z.w = fmaf(e01.x, a1.y, z.w);
    z.x = fmaf(e01.y, b0.x, z.x); z.y = fmaf(e01.y, b0.y, z.y);
    z.z = fmaf(e01.y, b1.x, z.z); z.w = fmaf(e01.y, b1.y, z.w);
    z.x = fmaf(e23.x, c0.x, z.x); z.y = fmaf(e23.x, c0.y, z.y);
    z.z = fmaf(e23.x, c1.x, z.z); z.w = fmaf(e23.x, c1.y, z.w);
    z.x = fmaf(e23.y, d0.x, z.x); z.y = fmaf(e23.y, d0.y, z.y);
    z.z = fmaf(e23.y, d1.x, z.z); z.w = fmaf(e23.y, d1.y, z.w);

    acc.x += fmaxf(z.x, 0.f);
    acc.y += fmaxf(z.y, 0.f);
    acc.z += fmaxf(z.z, 0.f);
    acc.w += fmaxf(z.w, 0.f);
}

// ---- per-node gather-aggregate: 16 lanes per node, no atomics ----
__global__ __launch_bounds__(256) void agg_k(const uint4* __restrict__ rec,
                                             const int* __restrict__ start,
                                             const int* __restrict__ cnt,
                                             const unsigned* __restrict__ y,
                                             const float* __restrict__ b,
                                             float* __restrict__ hout) {
    int t = blockIdx.x * 256 + threadIdx.x;
    int g = t >> 4;
    int lane = t & 15;
    if (g >= N_NODES) return;

    int s0 = start[g];
    int deg = cnt[g];
    int s1 = s0 + deg;

    float4 bias = ((const float4*)b)[lane];
    float4 acc = make_float4(0.f, 0.f, 0.f, 0.f);

    int i = s0;
    for (; i + 2 <= s1; i += 2) {
        uint4 r0 = rec[i];
        uint4 r1 = rec[i + 1];
        edge_step(r0, y, lane, bias, acc);
        edge_step(r1, y, lane, bias, acc);
    }
    if (i < s1) {
        uint4 r0 = rec[i];
        edge_step(r0, y, lane, bias, acc);
    }

    float inv = 1.0f / (float)(deg > 1 ? deg : 1);
    float4 r;
    r.x = fmaxf(acc.x * inv, 0.f);
    r.y = fmaxf(acc.y * inv, 0.f);
    r.z = fmaxf(acc.z * inv, 0.f);
    r.w = fmaxf(acc.w * inv, 0.f);
    ((float4*)hout)[(size_t)g * 16 + lane] = r;
}

// ---- final fc ----
__global__ void fc_k(const float* __restrict__ h, const float* __restrict__ Wfc,
                     const float* __restrict__ bfc, float* __restrict__ out) {
    int t = blockIdx.x * 256 + threadIdx.x;
    if (t >= N_NODES * NCLS) return;
    int n = t / NCLS;
    int c = t - n * NCLS;
    const float* hr = h + (size_t)n * 64;
    float acc = bfc[c];
#pragma unroll
    for (int j = 0; j < 64; ++j) acc = fmaf(hr[j], Wfc[j * NCLS + c], acc);
    out[t] = acc;
}

extern "C" void kernel_launch(void* const* d_in, const int* in_sizes, int n_in,
                              void* d_out, int out_size, void* d_ws, size_t ws_size,
                              hipStream_t stream) {
    const float* nf  = (const float*)d_in[0];
    const float* ef  = (const float*)d_in[1];
    const int*   src = (const int*)d_in[2];
    const int*   dst = (const int*)d_in[3];
    const float* W0  = (const float*)d_in[4];
    const float* b0  = (const float*)d_in[5];
    const float* W1  = (const float*)d_in[6];
    const float* b1  = (const float*)d_in[7];
    const float* Wfc = (const float*)d_in[8];
    const float* bfc = (const float*)d_in[9];
    float* out = (float*)d_out;

    char* ws = (char*)d_ws;
    size_t off = 0;
    auto alloc = [&](size_t bytes) -> void* {
        void* p = ws + off;
        off = (off + bytes + 255) & ~(size_t)255;
        return p;
    };
    int*      cnt    = (int*)     alloc((size_t)N_NODES * 4);
    int*      esc    = (int*)     alloc((size_t)N_NODES * 4);
    int*      bsum   = (int*)     alloc((size_t)NBLK * 4);
    int*      boff   = (int*)     alloc((size_t)NBLK * 4);
    int*      start  = (int*)     alloc((size_t)(N_NODES + 1) * 4);
    int*      cursor = (int*)     alloc((size_t)N_NODES * 4);
    uint4*    rec0   = (uint4*)   alloc((size_t)N_EDGES * 16);
    uint4*    rec1   = (uint4*)   alloc((size_t)N_EDGES * 16);
    unsigned* y      = (unsigned*)alloc((size_t)N_NODES * 256 * 2);  // fp16
    float*    hbuf   = (float*)   alloc((size_t)N_NODES * 64 * 4);

    hipMemsetAsync(cnt, 0, (size_t)N_NODES * 4, stream);

    // CSR build
    hist_k<<<(N_EDGES + 255) / 256, 256, 0, stream>>>(dst, cnt);
    blk_scan_k<<<NBLK, 256, 0, stream>>>(cnt, esc, bsum);
    bsum_scan_k<<<1, 256, 0, stream>>>(bsum, boff, start);
    finalize_k<<<NBLK, 256, 0, stream>>>(esc, boff, start, cursor);
    scatter_k<<<(N_EDGES + 255) / 256, 256, 0, stream>>>(src, dst, ef, cursor, rec0, rec1);

    int tgrid = (N_NODES + 31) / 32;
    int agrid = (N_NODES * 16 + 255) / 256;

    // layer 0
    transform_k<<<tgrid, 256, 0, stream>>>(nf, W0, y);
    agg_k<<<agrid, 256, 0, stream>>>(rec0, start, cnt, y, b0, hbuf);

    // layer 1
    transform_k<<<tgrid, 256, 0, stream>>>(hbuf, W1, y);
    agg_k<<<agrid, 256, 0, stream>>>(rec1, start, cnt, y, b1, hbuf);

    // classifier
    fc_k<<<(N_NODES * NCLS + 255) / 256, 256, 0, stream>>>(hbuf, Wfc, bfc, out);
}

// Round 5
// 308.622 us; speedup vs baseline: 3.6236x; 1.0442x over previous
//
#include <hip/hip_runtime.h>
#include <hip/hip_fp16.h>

#define N_NODES 50000
#define N_EDGES 500000
#define DIM 64
#define KDIM 4
#define HID 64
#define NCLS 40
#define NBLK ((N_NODES + 255) / 256)   // 196

__device__ inline unsigned pack2(float a, float b) {
    __half2 h = __floats2half2_rn(a, b);
    return *(unsigned*)&h;
}
__device__ inline float2 unpack2(unsigned u) {
    __half2 h = *(__half2*)&u;
    return __half22float2(h);
}

// ---- histogram of dst (in-degree) ----
__global__ void hist_k(const int* __restrict__ dst, int* __restrict__ cnt) {
    int e = blockIdx.x * 256 + threadIdx.x;
    if (e < N_EDGES) atomicAdd(&cnt[dst[e]], 1);
}

// ---- single-kernel scan: per-block scan + publish + parallel lookback ----
// bflag/bval zeroed by host memset each launch. 196 blocks co-resident on 256 CUs.
__global__ __launch_bounds__(256) void scan_k(const int* __restrict__ cnt,
                                              int* __restrict__ start,
                                              int* __restrict__ cursor,
                                              volatile int* __restrict__ bflag,
                                              volatile int* __restrict__ bval) {
    __shared__ int ls[256];
    __shared__ int sbase;
    __shared__ int ok_all;
    int b = blockIdx.x, t = threadIdx.x;
    int n = b * 256 + t;
    int v = (n < N_NODES) ? cnt[n] : 0;
    ls[t] = v;
    __syncthreads();
#pragma unroll
    for (int off = 1; off < 256; off <<= 1) {
        int u = (t >= off) ? ls[t - off] : 0;
        __syncthreads();
        ls[t] += u;
        __syncthreads();
    }
    int incl = ls[t];
    int total = ls[255];
    __syncthreads();

    if (t == 0) {
        bval[b] = total;
        __threadfence();          // publish value before flag
        bflag[b] = 1;
    }

    if (b > 0) {
        // parallel lookback: wait until ALL predecessors have published
        for (;;) {
            int f = (t < b) ? bflag[t] : 1;
            if (t == 0) ok_all = 1;
            __syncthreads();
            if (!f) ok_all = 0;
            __syncthreads();
            if (ok_all) break;
        }
        __threadfence();
        int pv = (t < b) ? bval[t] : 0;
        ls[t] = pv;
        __syncthreads();
#pragma unroll
        for (int off = 128; off > 0; off >>= 1) {
            if (t < off) ls[t] += ls[t + off];
            __syncthreads();
        }
        if (t == 0) sbase = ls[0];
        __syncthreads();
    } else {
        if (t == 0) sbase = 0;
        __syncthreads();
    }

    int excl = sbase + incl - v;
    if (n < N_NODES) { start[n] = excl; cursor[n] = excl; }
    if (n == 0) start[N_NODES] = N_EDGES;
}

// ---- counting-sort scatter: ONE interleaved 32B record per edge ----
// rec[2*pos] = layer0 {src, e(half4), 0}; rec[2*pos+1] = layer1
__global__ void scatter_k(const int* __restrict__ src, const int* __restrict__ dst,
                          const float* __restrict__ ef, int* __restrict__ cursor,
                          uint4* __restrict__ rec) {
    int e = blockIdx.x * 256 + threadIdx.x;
    if (e < N_EDGES) {
        int d = dst[e];
        int pos = atomicAdd(&cursor[d], 1);
        int sn = src[e];
        float4 f0 = ((const float4*)ef)[e];
        float4 f1 = ((const float4*)ef)[N_EDGES + e];
        rec[2 * pos]     = make_uint4((unsigned)sn, pack2(f0.x, f0.y), pack2(f0.z, f0.w), 0u);
        rec[2 * pos + 1] = make_uint4((unsigned)sn, pack2(f1.x, f1.y), pack2(f1.z, f1.w), 0u);
    }
}

// ---- node transform: y[n, k*64+h] = sum_d hin[n,d] * W[(k*64+d)*64+h], fp16 out ----
__global__ __launch_bounds__(256) void transform_k(const float* __restrict__ hin,
                                                   const float* __restrict__ W,
                                                   unsigned* __restrict__ y) {
    __shared__ float sW[KDIM * 64 * 64];   // 64 KB
    __shared__ float sh[32 * 65];
    int t = threadIdx.x;

    const float4* W4 = (const float4*)W;
    float4* sW4 = (float4*)sW;
#pragma unroll
    for (int i = 0; i < 16; ++i) sW4[t + 256 * i] = W4[t + 256 * i];

    int n0 = blockIdx.x * 32;
#pragma unroll
    for (int i = 0; i < 2; ++i) {
        int idx = t + 256 * i;
        int nl = idx >> 4;
        int dg = idx & 15;
        int n = n0 + nl;
        float4 v = make_float4(0.f, 0.f, 0.f, 0.f);
        if (n < N_NODES) v = ((const float4*)hin)[(size_t)n * 16 + dg];
        sh[nl * 65 + dg * 4 + 0] = v.x;
        sh[nl * 65 + dg * 4 + 1] = v.y;
        sh[nl * 65 + dg * 4 + 2] = v.z;
        sh[nl * 65 + dg * 4 + 3] = v.w;
    }
    __syncthreads();

    int nl = t & 15;
    int cg = t >> 4;
    int k = cg >> 2;
    int hc0 = (cg & 3) * 16;

    float acc0[16], acc1[16];
#pragma unroll
    for (int j = 0; j < 16; ++j) { acc0[j] = 0.f; acc1[j] = 0.f; }

    for (int d = 0; d < 64; ++d) {
        float a0 = sh[nl * 65 + d];
        float a1 = sh[(nl + 16) * 65 + d];
        const float* wr = &sW[k * 4096 + d * 64 + hc0];
#pragma unroll
        for (int j = 0; j < 16; ++j) {
            float w = wr[j];
            acc0[j] = fmaf(a0, w, acc0[j]);
            acc1[j] = fmaf(a1, w, acc1[j]);
        }
    }

    int n_a = n0 + nl, n_b = n0 + nl + 16;
    int cbase = k * 64 + hc0;
    if (n_a < N_NODES) {
        uint4* o = (uint4*)(y + ((size_t)n_a * 256 + cbase) / 2);
        o[0] = make_uint4(pack2(acc0[0], acc0[1]), pack2(acc0[2], acc0[3]),
                          pack2(acc0[4], acc0[5]), pack2(acc0[6], acc0[7]));
        o[1] = make_uint4(pack2(acc0[8], acc0[9]), pack2(acc0[10], acc0[11]),
                          pack2(acc0[12], acc0[13]), pack2(acc0[14], acc0[15]));
    }
    if (n_b < N_NODES) {
        uint4* o = (uint4*)(y + ((size_t)n_b * 256 + cbase) / 2);
        o[0] = make_uint4(pack2(acc1[0], acc1[1]), pack2(acc1[2], acc1[3]),
                          pack2(acc1[4], acc1[5]), pack2(acc1[6], acc1[7]));
        o[1] = make_uint4(pack2(acc1[8], acc1[9]), pack2(acc1[10], acc1[11]),
                          pack2(acc1[12], acc1[13]), pack2(acc1[14], acc1[15]));
    }
}

// ---- per-edge inner step (fp16 y) ----
__device__ inline void edge_step(const uint4 r, const unsigned* __restrict__ y,
                                 int lane, const float4 bias, float4& acc) {
    int sn = (int)r.x;
    float2 e01 = unpack2(r.y);
    float2 e23 = unpack2(r.z);
    const uint2* yb = (const uint2*)(y + (size_t)sn * 128);  // 256 halfs
    uint2 q0 = yb[lane];
    uint2 q1 = yb[16 + lane];
    uint2 q2 = yb[32 + lane];
    uint2 q3 = yb[48 + lane];

    float2 a0 = unpack2(q0.x), a1 = unpack2(q0.y);
    float2 b0 = unpack2(q1.x), b1 = unpack2(q1.y);
    float2 c0 = unpack2(q2.x), c1 = unpack2(q2.y);
    float2 d0 = unpack2(q3.x), d1 = unpack2(q3.y);

    float4 z = bias;
    z.x = fmaf(e01.x, a0.x, z.x); z.y = fmaf(e01.x, a0.y, z.y);
    z.z = fmaf(e01.x, a1.x, z.z); z.w = fmaf(e01.x, a1.y, z.w);
    z.x = fmaf(e01.y, b0.x, z.x); z.y = fmaf(e01.y, b0.y, z.y);
    z.z = fmaf(e01.y, b1.x, z.z); z.w = fmaf(e01.y, b1.y, z.w);
    z.x = fmaf(e23.x, c0.x, z.x); z.y = fmaf(e23.x, c0.y, z.y);
    z.z = fmaf(e23.x, c1.x, z.z); z.w = fmaf(e23.x, c1.y, z.w);
    z.x = fmaf(e23.y, d0.x, z.x); z.y = fmaf(e23.y, d0.y, z.y);
    z.z = fmaf(e23.y, d1.x, z.z); z.w = fmaf(e23.y, d1.y, z.w);

    acc.x += fmaxf(z.x, 0.f);
    acc.y += fmaxf(z.y, 0.f);
    acc.z += fmaxf(z.z, 0.f);
    acc.w += fmaxf(z.w, 0.f);
}

// ---- aggregate core: returns mean+relu float4 for (g, lane) ----
__device__ inline float4 agg_core(const uint4* __restrict__ rec2,
                                  const int* __restrict__ start,
                                  const int* __restrict__ cnt,
                                  const unsigned* __restrict__ y,
                                  const float* __restrict__ b,
                                  int g, int lane) {
    int s0 = start[g];
    int deg = cnt[g];
    int s1 = s0 + deg;

    float4 bias = ((const float4*)b)[lane];
    float4 acc = make_float4(0.f, 0.f, 0.f, 0.f);

    int i = s0;
    for (; i + 2 <= s1; i += 2) {
        uint4 r0 = rec2[2 * i];
        uint4 r1 = rec2[2 * (i + 1)];
        edge_step(r0, y, lane, bias, acc);
        edge_step(r1, y, lane, bias, acc);
    }
    if (i < s1) {
        uint4 r0 = rec2[2 * i];
        edge_step(r0, y, lane, bias, acc);
    }

    float inv = 1.0f / (float)(deg > 1 ? deg : 1);
    float4 r;
    r.x = fmaxf(acc.x * inv, 0.f);
    r.y = fmaxf(acc.y * inv, 0.f);
    r.z = fmaxf(acc.z * inv, 0.f);
    r.w = fmaxf(acc.w * inv, 0.f);
    return r;
}

// ---- layer-0 aggregate: write h to global ----
__global__ __launch_bounds__(256) void agg_k(const uint4* __restrict__ rec2,
                                             const int* __restrict__ start,
                                             const int* __restrict__ cnt,
                                             const unsigned* __restrict__ y,
                                             const float* __restrict__ b,
                                             float* __restrict__ hout) {
    int t = blockIdx.x * 256 + threadIdx.x;
    int g = t >> 4;
    int lane = t & 15;
    float4 r = agg_core(rec2, start, cnt, y, b, g, lane);
    ((float4*)hout)[(size_t)g * 16 + lane] = r;
}

// ---- layer-1 aggregate fused with final fc (block = 16 nodes) ----
__global__ __launch_bounds__(256) void agg_fc_k(const uint4* __restrict__ rec2,
                                                const int* __restrict__ start,
                                                const int* __restrict__ cnt,
                                                const unsigned* __restrict__ y,
                                                const float* __restrict__ b,
                                                const float* __restrict__ Wfc,
                                                const float* __restrict__ bfc,
                                                float* __restrict__ out) {
    __shared__ float sh_h[16 * 65];
    __shared__ float sWfc[64 * NCLS];
    __shared__ float sbfc[NCLS];
    int t = threadIdx.x;

    // stage Wfc/bfc
    for (int i = t; i < 64 * NCLS; i += 256) sWfc[i] = Wfc[i];
    if (t < NCLS) sbfc[t] = bfc[t];

    int nl = t >> 4;
    int lane = t & 15;
    int g = blockIdx.x * 16 + nl;   // grid is exact: 3125*16 = 50000

    float4 r = agg_core(rec2, start, cnt, y, b, g, lane);
    sh_h[nl * 65 + lane * 4 + 0] = r.x;
    sh_h[nl * 65 + lane * 4 + 1] = r.y;
    sh_h[nl * 65 + lane * 4 + 2] = r.z;
    sh_h[nl * 65 + lane * 4 + 3] = r.w;
    __syncthreads();

    for (int item = t; item < 16 * NCLS; item += 256) {
        int rn = item / NCLS;
        int c = item - rn * NCLS;
        float acc = sbfc[c];
        const float* hr = &sh_h[rn * 65];
#pragma unroll
        for (int j = 0; j < 64; ++j) acc = fmaf(hr[j], sWfc[j * NCLS + c], acc);
        out[(size_t)(blockIdx.x * 16 + rn) * NCLS + c] = acc;
    }
}

extern "C" void kernel_launch(void* const* d_in, const int* in_sizes, int n_in,
                              void* d_out, int out_size, void* d_ws, size_t ws_size,
                              hipStream_t stream) {
    const float* nf  = (const float*)d_in[0];
    const float* ef  = (const float*)d_in[1];
    const int*   src = (const int*)d_in[2];
    const int*   dst = (const int*)d_in[3];
    const float* W0  = (const float*)d_in[4];
    const float* b0  = (const float*)d_in[5];
    const float* W1  = (const float*)d_in[6];
    const float* b1  = (const float*)d_in[7];
    const float* Wfc = (const float*)d_in[8];
    const float* bfc = (const float*)d_in[9];
    float* out = (float*)d_out;

    char* ws = (char*)d_ws;
    size_t off = 0;
    auto alloc = [&](size_t bytes) -> void* {
        void* p = ws + off;
        off = (off + bytes + 255) & ~(size_t)255;
        return p;
    };
    // zeroed region: cnt (padded to 50176) + bflag(256) + bval(256)
    int*      zbuf   = (int*)     alloc((size_t)(50176 + 512) * 4);
    int*      cnt    = zbuf;
    int*      bflag  = zbuf + 50176;
    int*      bval   = zbuf + 50176 + 256;
    int*      start  = (int*)     alloc((size_t)(N_NODES + 1) * 4);
    int*      cursor = (int*)     alloc((size_t)N_NODES * 4);
    uint4*    rec    = (uint4*)   alloc((size_t)N_EDGES * 32);   // interleaved L0/L1
    unsigned* y      = (unsigned*)alloc((size_t)N_NODES * 256 * 2);  // fp16
    float*    hbuf   = (float*)   alloc((size_t)N_NODES * 64 * 4);

    hipMemsetAsync(zbuf, 0, (size_t)(50176 + 512) * 4, stream);

    // CSR build
    hist_k<<<(N_EDGES + 255) / 256, 256, 0, stream>>>(dst, cnt);
    scan_k<<<NBLK, 256, 0, stream>>>(cnt, start, cursor, bflag, bval);
    scatter_k<<<(N_EDGES + 255) / 256, 256, 0, stream>>>(src, dst, ef, cursor, rec);

    int tgrid = (N_NODES + 31) / 32;
    int agrid = N_NODES / 16;   // 3125, exact

    // layer 0
    transform_k<<<tgrid, 256, 0, stream>>>(nf, W0, y);
    agg_k<<<agrid, 256, 0, stream>>>(rec, start, cnt, y, b0, hbuf);

    // layer 1 + fused classifier
    transform_k<<<tgrid, 256, 0, stream>>>(hbuf, W1, y);
    agg_fc_k<<<agrid, 256, 0, stream>>>(rec + 1, start, cnt, y, b1, Wfc, bfc, out);
}

// Round 6
// 300.093 us; speedup vs baseline: 3.7266x; 1.0284x over previous
//
#include <hip/hip_runtime.h>
#include <hip/hip_fp16.h>

#define N_NODES 50000
#define N_EDGES 500000
#define DIM 64
#define KDIM 4
#define HID 64
#define NCLS 40
#define NBLK ((N_NODES + 255) / 256)   // 196

__device__ inline unsigned pack2(float a, float b) {
    __half2 h = __floats2half2_rn(a, b);
    return *(unsigned*)&h;
}
__device__ inline float2 unpack2(unsigned u) {
    __half2 h = *(__half2*)&u;
    return __half22float2(h);
}

// ---- histogram of dst (in-degree) ----
__global__ void hist_k(const int* __restrict__ dst, int* __restrict__ cnt) {
    int e = blockIdx.x * 256 + threadIdx.x;
    if (e < N_EDGES) atomicAdd(&cnt[dst[e]], 1);
}

// ---- single-kernel scan: per-block scan + publish + parallel lookback ----
__global__ __launch_bounds__(256) void scan_k(const int* __restrict__ cnt,
                                              int* __restrict__ start,
                                              int* __restrict__ cursor,
                                              volatile int* __restrict__ bflag,
                                              volatile int* __restrict__ bval) {
    __shared__ int ls[256];
    __shared__ int sbase;
    __shared__ int ok_all;
    int b = blockIdx.x, t = threadIdx.x;
    int n = b * 256 + t;
    int v = (n < N_NODES) ? cnt[n] : 0;
    ls[t] = v;
    __syncthreads();
#pragma unroll
    for (int off = 1; off < 256; off <<= 1) {
        int u = (t >= off) ? ls[t - off] : 0;
        __syncthreads();
        ls[t] += u;
        __syncthreads();
    }
    int incl = ls[t];
    int total = ls[255];
    __syncthreads();

    if (t == 0) {
        bval[b] = total;
        __threadfence();
        bflag[b] = 1;
    }

    if (b > 0) {
        for (;;) {
            int f = (t < b) ? bflag[t] : 1;
            if (t == 0) ok_all = 1;
            __syncthreads();
            if (!f) ok_all = 0;
            __syncthreads();
            if (ok_all) break;
        }
        __threadfence();
        int pv = (t < b) ? bval[t] : 0;
        ls[t] = pv;
        __syncthreads();
#pragma unroll
        for (int off = 128; off > 0; off >>= 1) {
            if (t < off) ls[t] += ls[t + off];
            __syncthreads();
        }
        if (t == 0) sbase = ls[0];
        __syncthreads();
    } else {
        if (t == 0) sbase = 0;
        __syncthreads();
    }

    int excl = sbase + incl - v;
    if (n < N_NODES) { start[n] = excl; cursor[n] = excl; }
    if (n == 0) start[N_NODES] = N_EDGES;
}

// ---- counting-sort scatter: ONE interleaved 32B record per edge ----
__global__ void scatter_k(const int* __restrict__ src, const int* __restrict__ dst,
                          const float* __restrict__ ef, int* __restrict__ cursor,
                          uint4* __restrict__ rec) {
    int e = blockIdx.x * 256 + threadIdx.x;
    if (e < N_EDGES) {
        int d = dst[e];
        int pos = atomicAdd(&cursor[d], 1);
        int sn = src[e];
        float4 f0 = ((const float4*)ef)[e];
        float4 f1 = ((const float4*)ef)[N_EDGES + e];
        rec[2 * pos]     = make_uint4((unsigned)sn, pack2(f0.x, f0.y), pack2(f0.z, f0.w), 0u);
        rec[2 * pos + 1] = make_uint4((unsigned)sn, pack2(f1.x, f1.y), pack2(f1.z, f1.w), 0u);
    }
}

// ---- node transform, split-k: blockIdx.y = kpair (k in {2*kpair, 2*kpair+1}) ----
// 64 nodes/block, 32KB W-slice + 16.6KB h-tile = 48.9KB LDS -> 3 blocks/CU
__global__ __launch_bounds__(256) void transform_k(const float* __restrict__ hin,
                                                   const float* __restrict__ W,
                                                   unsigned* __restrict__ y) {
    __shared__ float sW[2 * 64 * 64];      // 32 KB: two k-slices
    __shared__ float sh[64 * 65];          // 16.6 KB
    int t = threadIdx.x;
    int kpair = blockIdx.y;

    // stage W slice: 8192 floats = 2048 float4 / 256 threads = 8 each
    const float4* W4 = (const float4*)(W + (size_t)kpair * 2 * 4096);
    float4* sW4 = (float4*)sW;
#pragma unroll
    for (int i = 0; i < 8; ++i) sW4[t + 256 * i] = W4[t + 256 * i];

    int n0 = blockIdx.x * 64;
    // stage h tile: 64 nodes x 16 float4 = 1024 float4 -> 4 per thread
#pragma unroll
    for (int i = 0; i < 4; ++i) {
        int idx = t + 256 * i;        // 0..1023
        int nl = idx >> 4;            // 0..63
        int dg = idx & 15;
        int n = n0 + nl;
        float4 v = make_float4(0.f, 0.f, 0.f, 0.f);
        if (n < N_NODES) v = ((const float4*)hin)[(size_t)n * 16 + dg];
        sh[nl * 65 + dg * 4 + 0] = v.x;
        sh[nl * 65 + dg * 4 + 1] = v.y;
        sh[nl * 65 + dg * 4 + 2] = v.z;
        sh[nl * 65 + dg * 4 + 3] = v.w;
    }
    __syncthreads();

    // 256 threads = 8 col-groups (16 cols each over the 128 cols of this kpair)
    // x 32 node-slots; each slot handles nodes nl and nl+32
    int nl = t & 31;
    int cg = t >> 5;                  // 0..7
    int k_local = cg >> 2;            // 0..1
    int hc0 = (cg & 3) * 16;

    float acc0[16], acc1[16];
#pragma unroll
    for (int j = 0; j < 16; ++j) { acc0[j] = 0.f; acc1[j] = 0.f; }

    for (int d = 0; d < 64; ++d) {
        float a0 = sh[nl * 65 + d];
        float a1 = sh[(nl + 32) * 65 + d];
        const float* wr = &sW[k_local * 4096 + d * 64 + hc0];
#pragma unroll
        for (int j = 0; j < 16; ++j) {
            float w = wr[j];
            acc0[j] = fmaf(a0, w, acc0[j]);
            acc1[j] = fmaf(a1, w, acc1[j]);
        }
    }

    int n_a = n0 + nl, n_b = n0 + nl + 32;
    int cbase = (kpair * 2 + k_local) * 64 + hc0;
    if (n_a < N_NODES) {
        uint4* o = (uint4*)(y + ((size_t)n_a * 256 + cbase) / 2);
        o[0] = make_uint4(pack2(acc0[0], acc0[1]), pack2(acc0[2], acc0[3]),
                          pack2(acc0[4], acc0[5]), pack2(acc0[6], acc0[7]));
        o[1] = make_uint4(pack2(acc0[8], acc0[9]), pack2(acc0[10], acc0[11]),
                          pack2(acc0[12], acc0[13]), pack2(acc0[14], acc0[15]));
    }
    if (n_b < N_NODES) {
        uint4* o = (uint4*)(y + ((size_t)n_b * 256 + cbase) / 2);
        o[0] = make_uint4(pack2(acc1[0], acc1[1]), pack2(acc1[2], acc1[3]),
                          pack2(acc1[4], acc1[5]), pack2(acc1[6], acc1[7]));
        o[1] = make_uint4(pack2(acc1[8], acc1[9]), pack2(acc1[10], acc1[11]),
                          pack2(acc1[12], acc1[13]), pack2(acc1[14], acc1[15]));
    }
}

// ---- edge load/compute split for MLP ----
__device__ inline void load_edge(const uint4 r, const unsigned* __restrict__ y,
                                 int lane, uint2& q0, uint2& q1, uint2& q2, uint2& q3) {
    int sn = (int)r.x;
    const uint2* yb = (const uint2*)(y + (size_t)sn * 128);
    q0 = yb[lane];
    q1 = yb[16 + lane];
    q2 = yb[32 + lane];
    q3 = yb[48 + lane];
}

__device__ inline void compute_edge(const uint4 r, uint2 q0, uint2 q1, uint2 q2, uint2 q3,
                                    const float4 bias, float4& acc) {
    float2 e01 = unpack2(r.y);
    float2 e23 = unpack2(r.z);
    float2 a0 = unpack2(q0.x), a1 = unpack2(q0.y);
    float2 b0 = unpack2(q1.x), b1 = unpack2(q1.y);
    float2 c0 = unpack2(q2.x), c1 = unpack2(q2.y);
    float2 d0 = unpack2(q3.x), d1 = unpack2(q3.y);

    float4 z = bias;
    z.x = fmaf(e01.x, a0.x, z.x); z.y = fmaf(e01.x, a0.y, z.y);
    z.z = fmaf(e01.x, a1.x, z.z); z.w = fmaf(e01.x, a1.y, z.w);
    z.x = fmaf(e01.y, b0.x, z.x); z.y = fmaf(e01.y, b0.y, z.y);
    z.z = fmaf(e01.y, b1.x, z.z); z.w = fmaf(e01.y, b1.y, z.w);
    z.x = fmaf(e23.x, c0.x, z.x); z.y = fmaf(e23.x, c0.y, z.y);
    z.z = fmaf(e23.x, c1.x, z.z); z.w = fmaf(e23.x, c1.y, z.w);
    z.x = fmaf(e23.y, d0.x, z.x); z.y = fmaf(e23.y, d0.y, z.y);
    z.z = fmaf(e23.y, d1.x, z.z); z.w = fmaf(e23.y, d1.y, z.w);

    acc.x += fmaxf(z.x, 0.f);
    acc.y += fmaxf(z.y, 0.f);
    acc.z += fmaxf(z.z, 0.f);
    acc.w += fmaxf(z.w, 0.f);
}

// ---- aggregate core: unroll-4, batched loads ----
__device__ inline float4 agg_core(const uint4* __restrict__ rec2,
                                  const int* __restrict__ start,
                                  const int* __restrict__ cnt,
                                  const unsigned* __restrict__ y,
                                  const float* __restrict__ b,
                                  int g, int lane) {
    int s0 = start[g];
    int deg = cnt[g];
    int s1 = s0 + deg;

    float4 bias = ((const float4*)b)[lane];
    float4 acc = make_float4(0.f, 0.f, 0.f, 0.f);

    int i = s0;
    for (; i + 4 <= s1; i += 4) {
        uint4 r0 = rec2[2 * i + 0];
        uint4 r1 = rec2[2 * i + 2];
        uint4 r2 = rec2[2 * i + 4];
        uint4 r3 = rec2[2 * i + 6];
        uint2 a0, a1, a2, a3, b0, b1, b2, b3, c0, c1, c2, c3, d0, d1, d2, d3;
        load_edge(r0, y, lane, a0, a1, a2, a3);
        load_edge(r1, y, lane, b0, b1, b2, b3);
        load_edge(r2, y, lane, c0, c1, c2, c3);
        load_edge(r3, y, lane, d0, d1, d2, d3);
        compute_edge(r0, a0, a1, a2, a3, bias, acc);
        compute_edge(r1, b0, b1, b2, b3, bias, acc);
        compute_edge(r2, c0, c1, c2, c3, bias, acc);
        compute_edge(r3, d0, d1, d2, d3, bias, acc);
    }
    if (i + 2 <= s1) {
        uint4 r0 = rec2[2 * i + 0];
        uint4 r1 = rec2[2 * i + 2];
        uint2 a0, a1, a2, a3, b0, b1, b2, b3;
        load_edge(r0, y, lane, a0, a1, a2, a3);
        load_edge(r1, y, lane, b0, b1, b2, b3);
        compute_edge(r0, a0, a1, a2, a3, bias, acc);
        compute_edge(r1, b0, b1, b2, b3, bias, acc);
        i += 2;
    }
    if (i < s1) {
        uint4 r0 = rec2[2 * i];
        uint2 a0, a1, a2, a3;
        load_edge(r0, y, lane, a0, a1, a2, a3);
        compute_edge(r0, a0, a1, a2, a3, bias, acc);
    }

    float inv = 1.0f / (float)(deg > 1 ? deg : 1);
    float4 r;
    r.x = fmaxf(acc.x * inv, 0.f);
    r.y = fmaxf(acc.y * inv, 0.f);
    r.z = fmaxf(acc.z * inv, 0.f);
    r.w = fmaxf(acc.w * inv, 0.f);
    return r;
}

// ---- layer-0 aggregate ----
__global__ __launch_bounds__(256) void agg_k(const uint4* __restrict__ rec2,
                                             const int* __restrict__ start,
                                             const int* __restrict__ cnt,
                                             const unsigned* __restrict__ y,
                                             const float* __restrict__ b,
                                             float* __restrict__ hout) {
    int t = blockIdx.x * 256 + threadIdx.x;
    int g = t >> 4;
    int lane = t & 15;
    float4 r = agg_core(rec2, start, cnt, y, b, g, lane);
    ((float4*)hout)[(size_t)g * 16 + lane] = r;
}

// ---- layer-1 aggregate fused with final fc (block = 16 nodes) ----
__global__ __launch_bounds__(256) void agg_fc_k(const uint4* __restrict__ rec2,
                                                const int* __restrict__ start,
                                                const int* __restrict__ cnt,
                                                const unsigned* __restrict__ y,
                                                const float* __restrict__ b,
                                                const float* __restrict__ Wfc,
                                                const float* __restrict__ bfc,
                                                float* __restrict__ out) {
    __shared__ float sh_h[16 * 65];
    __shared__ float sWfcT[NCLS * 65];   // transposed, padded: [c*65 + j]
    __shared__ float sbfc[NCLS];
    int t = threadIdx.x;

    for (int i = t; i < 64 * NCLS; i += 256) {
        int j = i / NCLS;
        int c = i - j * NCLS;
        sWfcT[c * 65 + j] = Wfc[i];
    }
    if (t < NCLS) sbfc[t] = bfc[t];

    int nl = t >> 4;
    int lane = t & 15;
    int g = blockIdx.x * 16 + nl;   // grid exact: 3125*16 = 50000

    float4 r = agg_core(rec2, start, cnt, y, b, g, lane);
    sh_h[nl * 65 + lane * 4 + 0] = r.x;
    sh_h[nl * 65 + lane * 4 + 1] = r.y;
    sh_h[nl * 65 + lane * 4 + 2] = r.z;
    sh_h[nl * 65 + lane * 4 + 3] = r.w;
    __syncthreads();

    for (int item = t; item < 16 * NCLS; item += 256) {
        int rn = item / NCLS;
        int c = item - rn * NCLS;
        float acc = sbfc[c];
        const float* hr = &sh_h[rn * 65];
        const float* wc = &sWfcT[c * 65];
#pragma unroll
        for (int j = 0; j < 64; ++j) acc = fmaf(hr[j], wc[j], acc);
        out[(size_t)(blockIdx.x * 16 + rn) * NCLS + c] = acc;
    }
}

extern "C" void kernel_launch(void* const* d_in, const int* in_sizes, int n_in,
                              void* d_out, int out_size, void* d_ws, size_t ws_size,
                              hipStream_t stream) {
    const float* nf  = (const float*)d_in[0];
    const float* ef  = (const float*)d_in[1];
    const int*   src = (const int*)d_in[2];
    const int*   dst = (const int*)d_in[3];
    const float* W0  = (const float*)d_in[4];
    const float* b0  = (const float*)d_in[5];
    const float* W1  = (const float*)d_in[6];
    const float* b1  = (const float*)d_in[7];
    const float* Wfc = (const float*)d_in[8];
    const float* bfc = (const float*)d_in[9];
    float* out = (float*)d_out;

    char* ws = (char*)d_ws;
    size_t off = 0;
    auto alloc = [&](size_t bytes) -> void* {
        void* p = ws + off;
        off = (off + bytes + 255) & ~(size_t)255;
        return p;
    };
    int*      zbuf   = (int*)     alloc((size_t)(50176 + 512) * 4);
    int*      cnt    = zbuf;
    int*      bflag  = zbuf + 50176;
    int*      bval   = zbuf + 50176 + 256;
    int*      start  = (int*)     alloc((size_t)(N_NODES + 1) * 4);
    int*      cursor = (int*)     alloc((size_t)N_NODES * 4);
    uint4*    rec    = (uint4*)   alloc((size_t)N_EDGES * 32);
    unsigned* y      = (unsigned*)alloc((size_t)N_NODES * 256 * 2);
    float*    hbuf   = (float*)   alloc((size_t)N_NODES * 64 * 4);

    hipMemsetAsync(zbuf, 0, (size_t)(50176 + 512) * 4, stream);

    hist_k<<<(N_EDGES + 255) / 256, 256, 0, stream>>>(dst, cnt);
    scan_k<<<NBLK, 256, 0, stream>>>(cnt, start, cursor, bflag, bval);
    scatter_k<<<(N_EDGES + 255) / 256, 256, 0, stream>>>(src, dst, ef, cursor, rec);

    dim3 tgrid((N_NODES + 63) / 64, 2);   // 782 x 2 (split-k)
    int agrid = N_NODES / 16;             // 3125, exact

    // layer 0
    transform_k<<<tgrid, 256, 0, stream>>>(nf, W0, y);
    agg_k<<<agrid, 256, 0, stream>>>(rec, start, cnt, y, b0, hbuf);

    // layer 1 + fused classifier
    transform_k<<<tgrid, 256, 0, stream>>>(hbuf, W1, y);
    agg_fc_k<<<agrid, 256, 0, stream>>>(rec + 1, start, cnt, y, b1, Wfc, bfc, out);
}